// Round 6
// baseline (75.031 us; speedup 1.0000x reference)
//
#include <hip/hip_runtime.h>

#define N 1024
#define D 128
#define PAD 132   // 128+4: rows 16B-aligned (528 B); A reads 4 distinct banks,
                  // B reads 2-way alias (free). Bank = (4*row + d) % 32.

// ---------------------------------------------------------------------------
// Phase A: E[i][j] = exp(relu(sum_d |x[i][d]-x[j][d]| * w[d] + bias)), plus
// per-block row partials part[row][bx] (every slot written -> poisoned ws
// needs no init, no atomics).
//
// ROUND-6 CHANGE: rebalance LDS-instr vs VALU. All prior rounds were
// LDS-return-path bound: micro 4x2 = 7 ds_read_b128 (84 pipe-cyc) per
// 128 VALU-cyc chunk -> 2.6x oversubscribed; latency/occupancy fixes (R3-R5)
// were null because the pipe itself was the constraint. Balance condition
// 48*L <= V. New: split-d 4 x micro 8x4 -> L=12 (W in regs, no W read),
// V=512 -> 576~512, near-balanced. The 512-cyc FMA block per chunk also
// self-hides ds latency, so 2 waves/SIMD (1 block/CU) suffices.
//
// Geometry: tile 64x64, 512 thr = 4 d-groups x 128 thr; group g handles
// d in [32g,32g+32), micro 8 rows x 4 cols. Grid (16,16)=256 blocks, 1/CU.
// LDS: 2x64xPAD = 67.6 KB. Combine: groups 1-3 dump acc into the dead tile
// space ([3][128][36] f32, f4-aligned), group 0 sums + runs the epilogue.
// ---------------------------------------------------------------------------
__global__ __launch_bounds__(512, 2) void scores_kernel(
    const float* __restrict__ x, const float* __restrict__ w,
    const float* __restrict__ bias, float* __restrict__ E,
    float* __restrict__ part) {
  __shared__ float smem[2 * 64 * PAD];   // sxi | sxj ; combine buffer aliases
  float* sxi = smem;
  float* sxj = smem + 64 * PAD;

  const int t  = threadIdx.x;
  const int bi = blockIdx.y * 64;
  const int bj = blockIdx.x * 64;

  // ---- stage both 64-row tiles: coalesced float4, one barrier --------------
  {
    const int c  = t & 31;   // float4 column 0..31
    const int r0 = t >> 5;   // 0..15
    #pragma unroll
    for (int p = 0; p < 4; ++p) {
      const int r = r0 + p * 16;
      const float4 vi = reinterpret_cast<const float4*>(x)[(bi + r) * 32 + c];
      *reinterpret_cast<float4*>(&sxi[r * PAD + c * 4]) = vi;
      const float4 vj = reinterpret_cast<const float4*>(x)[(bj + r) * 32 + c];
      *reinterpret_cast<float4*>(&sxj[r * PAD + c * 4]) = vj;
    }
  }

  // d-group (wave-uniform: 128-thr groups = 2 waves each)
  const int g  = __builtin_amdgcn_readfirstlane(t >> 7);   // 0..3
  const int s  = t & 127;                                  // slot in group
  const int tx = s & 15;   // cols tx + 16*b, b=0..3
  const int ty = s >> 4;   // rows ty + 8*a,  a=0..7
  const int d0 = g * 32;   // this group's d-range base

  // ---- W slice preloaded to registers (uniform -> scalar loads, hoisted) ---
  float4 W[8];
  #pragma unroll
  for (int c = 0; c < 8; ++c)
    W[c] = reinterpret_cast<const float4*>(w)[g * 8 + c];

  __syncthreads();

  float acc[8][4];
  #pragma unroll
  for (int a = 0; a < 8; ++a)
    #pragma unroll
    for (int b = 0; b < 4; ++b) acc[a][b] = 0.f;

  // ---- d-loop: 8 chunks of 4 d-values; pure ds_read + VALU -----------------
  #pragma unroll
  for (int dc = 0; dc < 8; ++dc) {
    const int d = d0 + dc * 4;
    float4 A[8], B[4];
    #pragma unroll
    for (int a = 0; a < 8; ++a)   // 4 distinct addrs/wave, distinct banks
      A[a] = *reinterpret_cast<const float4*>(&sxi[(ty + 8 * a) * PAD + d]);
    #pragma unroll
    for (int b = 0; b < 4; ++b)   // 16 distinct addrs/wave, 2-way alias (free)
      B[b] = *reinterpret_cast<const float4*>(&sxj[(tx + 16 * b) * PAD + d]);

    #pragma unroll
    for (int a = 0; a < 8; ++a) {
      #pragma unroll
      for (int b = 0; b < 4; ++b) {
        float v = acc[a][b];
        v = fmaf(fabsf(A[a].x - B[b].x), W[dc].x, v);
        v = fmaf(fabsf(A[a].y - B[b].y), W[dc].y, v);
        v = fmaf(fabsf(A[a].z - B[b].z), W[dc].z, v);
        v = fmaf(fabsf(A[a].w - B[b].w), W[dc].w, v);
        acc[a][b] = v;
      }
    }
  }
  __syncthreads();   // tiles dead; smem becomes the combine buffer

  // ---- combine the 4 d-partials: g1-3 write, g0 sums -----------------------
  // layout [3][128][36] f32: f4-aligned, 55.3 KB < 67.6 KB available
  float* comb = smem;
  if (g > 0) {
    float* dst = comb + ((g - 1) * 128 + s) * 36;
    #pragma unroll
    for (int a = 0; a < 8; ++a) {
      float4 v = make_float4(acc[a][0], acc[a][1], acc[a][2], acc[a][3]);
      *reinterpret_cast<float4*>(&dst[a * 4]) = v;
    }
  }
  __syncthreads();

  if (g == 0) {
    #pragma unroll
    for (int q = 0; q < 3; ++q) {
      const float* src = comb + (q * 128 + s) * 36;
      #pragma unroll
      for (int a = 0; a < 8; ++a) {
        const float4 v = *reinterpret_cast<const float4*>(&src[a * 4]);
        acc[a][0] += v.x; acc[a][1] += v.y; acc[a][2] += v.z; acc[a][3] += v.w;
      }
    }

    // ---- epilogue: bias + relu + exp (no max-sub: scores >= 0, bounded,
    // fp32-safe; identical numerics passed rounds 2-5, absmax 0.0) ----------
    const float bv = bias[0];
    #pragma unroll
    for (int a = 0; a < 8; ++a) {
      float p = 0.f;
      #pragma unroll
      for (int b = 0; b < 4; ++b) {
        const float ev = __expf(fmaxf(acc[a][b] + bv, 0.f));
        acc[a][b] = ev;
        p += ev;
      }
      // reduce across the 16-lane tx group (xor<16 keeps ty fixed)
      #pragma unroll
      for (int o = 1; o < 16; o <<= 1) p += __shfl_xor(p, o, 64);
      if (tx == 0) part[(bi + ty + 8 * a) * 16 + blockIdx.x] = p;
    }

    #pragma unroll
    for (int a = 0; a < 8; ++a) {
      const int row = bi + ty + 8 * a;
      #pragma unroll
      for (int b = 0; b < 4; ++b)
        E[row * N + bj + tx + 16 * b] = acc[a][b];
    }
  }
}

// ---------------------------------------------------------------------------
// Phase B: scale pass. One block per row: sum 16 partials (L2-hot), scale.
// ---------------------------------------------------------------------------
__global__ __launch_bounds__(256) void scale_kernel(
    float* __restrict__ S, const float* __restrict__ part) {
  const int row = blockIdx.x;
  const int t   = threadIdx.x;

  float p = part[row * 16 + (t & 15)];
  #pragma unroll
  for (int o = 1; o < 16; o <<= 1) p += __shfl_xor(p, o, 64);
  const float r = 1.0f / p;

  float4* rowp = reinterpret_cast<float4*>(S + row * N);
  float4 v = rowp[t];
  v.x *= r; v.y *= r; v.z *= r; v.w *= r;
  rowp[t] = v;
}

extern "C" void kernel_launch(void* const* d_in, const int* in_sizes, int n_in,
                              void* d_out, int out_size, void* d_ws, size_t ws_size,
                              hipStream_t stream) {
  const float* x = (const float*)d_in[0];
  const float* w = (const float*)d_in[1];
  const float* b = (const float*)d_in[2];
  float* out  = (float*)d_out;
  float* part = (float*)d_ws;   // [1024][16] f32 = 64 KB, every slot written

  dim3 grid(N / 64, N / 64);    // (16,16) = 256 blocks, 1/CU, 2 waves/SIMD
  scores_kernel<<<grid, 512, 0, stream>>>(x, w, b, out, part);
  scale_kernel<<<N, 256, 0, stream>>>(out, part);
}